// Round 3
// baseline (774.900 us; speedup 1.0000x reference)
//
#include <hip/hip_runtime.h>

#define NN 3070      // nodes
#define NF 128       // in features
#define NO 64        // gcn out features
#define NH 50        // hidden
#define NE 49120     // edges
#define NB 128       // batch (= rnn seq len)
#define BCH 32       // batches per chunk
#define NCHUNK 4
#define MCH (BCH * NN)   // 98240 rows per gemm chunk
#define GCAP 1024        // staged edges per 16-node gather block

// ---------------- edge preprocessing ----------------

__global__ __launch_bounds__(256) void zero_kernel(int* __restrict__ p, int n) {
  int i = blockIdx.x * 256 + threadIdx.x;
  if (i < n) p[i] = 0;
}

__global__ __launch_bounds__(256) void mark_kernel(const int* __restrict__ ei, int* __restrict__ mark) {
  int i = blockIdx.x * 256 + threadIdx.x;
  if (i < 2 * NE) mark[ei[i]] = 1;
}

// exclusive prefix scan of n<=3072 ints, single block of 1024 threads, 3 items/thread
__global__ __launch_bounds__(1024) void exscan_kernel(const int* __restrict__ in, int* __restrict__ out,
                                                      int n, int write_total) {
  __shared__ int part[1024];
  int tid = threadIdx.x;
  int base = tid * 3;
  int v0 = (base + 0 < n) ? in[base + 0] : 0;
  int v1 = (base + 1 < n) ? in[base + 1] : 0;
  int v2 = (base + 2 < n) ? in[base + 2] : 0;
  int s = v0 + v1 + v2;
  part[tid] = s;
  __syncthreads();
  for (int off = 1; off < 1024; off <<= 1) {
    int t = (tid >= off) ? part[tid - off] : 0;
    __syncthreads();
    part[tid] += t;
    __syncthreads();
  }
  int run = part[tid] - s;  // exclusive base of this thread's chunk
  if (base + 0 < n) out[base + 0] = run; run += v0;
  if (base + 1 < n) out[base + 1] = run; run += v1;
  if (base + 2 < n) out[base + 2] = run;
  if (write_total && tid == 1023) out[n] = part[1023];
}

__global__ __launch_bounds__(256) void remap_deg_kernel(const int* __restrict__ ei, const float* __restrict__ ew,
    const int* __restrict__ ranks, int* __restrict__ srcr, int* __restrict__ dstr,
    int* __restrict__ degc, float* __restrict__ degw) {
  int e = blockIdx.x * 256 + threadIdx.x;
  if (e >= NE) return;
  int s = ranks[ei[e]];
  int d = ranks[ei[NE + e]];
  srcr[e] = s;
  dstr[e] = d;
  atomicAdd(&degc[d], 1);
  atomicAdd(&degw[d], ew[e]);
}

__global__ __launch_bounds__(256) void dinv_kernel(const float* __restrict__ degw,
    float* __restrict__ dinv, float* __restrict__ selfn) {
  int n = blockIdx.x * 256 + threadIdx.x;
  if (n >= NN) return;
  float dg = degw[n] + 1.0f;  // + self-loop weight 1
  float di = rsqrtf(dg);      // dg >= 1 always
  dinv[n] = di;
  selfn[n] = di * di;         // self-loop message norm
}

__global__ __launch_bounds__(256) void csr_fill_kernel(const float* __restrict__ ew, const int* __restrict__ srcr,
    const int* __restrict__ dstr, const int* __restrict__ rowptr, int* __restrict__ cursor,
    const float* __restrict__ dinv, int* __restrict__ csr_src, float* __restrict__ csr_norm) {
  int e = blockIdx.x * 256 + threadIdx.x;
  if (e >= NE) return;
  int d = dstr[e];
  int s = srcr[e];
  int pos = rowptr[d] + atomicAdd(&cursor[d], 1);
  csr_src[pos] = s;
  csr_norm[pos] = dinv[s] * ew[e] * dinv[d];
}

// ---------------- GEMM: xw = A(M,128) @ W(128,64), fp32 ----------------
// 128-row tile/block, 256 threads, micro-tile 4 rows x 8 cols (acc=32 VGPRs).
// K chunked by 32 so LDS = 34.8K(A) + 8K(W) = 42K. All LDS access <=2-way (free).
__global__ __launch_bounds__(256) void gemm_kernel(const float* __restrict__ A,
    const float* __restrict__ W, float* __restrict__ out, int M) {
  __shared__ float As[128 * 68];   // [row][k], stride 68 -> A-read bank (4*rg+k)%32, 2-way
  __shared__ float Ws[32 * 64];    // [k][col], broadcast reads
  int tid = threadIdx.x;
  int row0 = blockIdx.x * 128;
  int rg = tid >> 3;        // 0..31 : rows rg + 32*i
  int cg = tid & 7;         // cols cg*8 .. cg*8+7
  int c0 = cg * 8;
  float acc[4][8];
#pragma unroll
  for (int i = 0; i < 4; ++i)
#pragma unroll
    for (int j = 0; j < 8; ++j) acc[i][j] = 0.f;

  for (int kc = 0; kc < 4; ++kc) {
    // stage A chunk: 128 rows x 32 k (4 float4 / thread)
#pragma unroll
    for (int j = 0; j < 4; ++j) {
      int f = tid + 256 * j;        // 0..1023
      int r = f >> 3, kq = f & 7;
      int grow = row0 + r;
      float4 v = make_float4(0.f, 0.f, 0.f, 0.f);
      if (grow < M) v = *(const float4*)&A[(size_t)grow * NF + kc * 32 + kq * 4];
      *(float4*)&As[r * 68 + kq * 4] = v;
    }
    // stage W chunk: 32 k x 64 cols (2 float4 / thread)
#pragma unroll
    for (int j = 0; j < 2; ++j) {
      int f = tid + 256 * j;        // 0..511
      int kk = f >> 4, cq = f & 15;
      *(float4*)&Ws[kk * 64 + cq * 4] = *(const float4*)&W[(size_t)(kc * 32 + kk) * NO + cq * 4];
    }
    __syncthreads();
#pragma unroll 2
    for (int k4 = 0; k4 < 32; k4 += 4) {
      float4 a[4];
#pragma unroll
      for (int i = 0; i < 4; ++i) a[i] = *(const float4*)&As[(rg + 32 * i) * 68 + k4];
#pragma unroll
      for (int m = 0; m < 4; ++m) {
        float4 w0 = *(const float4*)&Ws[(k4 + m) * 64 + c0];
        float4 w1 = *(const float4*)&Ws[(k4 + m) * 64 + c0 + 4];
#pragma unroll
        for (int i = 0; i < 4; ++i) {
          float av = (m == 0) ? a[i].x : (m == 1) ? a[i].y : (m == 2) ? a[i].z : a[i].w;
          acc[i][0] += av * w0.x; acc[i][1] += av * w0.y;
          acc[i][2] += av * w0.z; acc[i][3] += av * w0.w;
          acc[i][4] += av * w1.x; acc[i][5] += av * w1.y;
          acc[i][6] += av * w1.z; acc[i][7] += av * w1.w;
        }
      }
    }
    __syncthreads();
  }
#pragma unroll
  for (int i = 0; i < 4; ++i) {
    int r = row0 + rg + 32 * i;
    if (r < M) {
      *(float4*)&out[(size_t)r * NO + c0] = make_float4(acc[i][0], acc[i][1], acc[i][2], acc[i][3]);
      *(float4*)&out[(size_t)r * NO + c0 + 4] = make_float4(acc[i][4], acc[i][5], acc[i][6], acc[i][7]);
    }
  }
}

// ---------------- GCN aggregation: atomic-free CSR gather ----------------
// Block = 16 nodes x 16 float4-feats; grid.y = batch in chunk.
// Edge meta (src,norm) for the block's 16 nodes staged in LDS once -> inner
// loop is 1 float4 VMEM + 4 FMA per edge, 2x unrolled.
__global__ __launch_bounds__(256) void gather_kernel(const float4* __restrict__ xw,
    const int* __restrict__ rowptr, const int* __restrict__ csr_src, const float* __restrict__ csr_norm,
    const float* __restrict__ selfn, const float* __restrict__ bias, float4* __restrict__ outg, int b0) {
  __shared__ int s_src[GCAP];
  __shared__ float s_nrm[GCAP];
  int tid = threadIdx.x;
  int f4 = tid & 15, nl = tid >> 4;
  int nb = blockIdx.x * 16;
  int b = blockIdx.y;
  int nend = nb + 16 < NN ? nb + 16 : NN;
  int be0 = rowptr[nb], be1 = rowptr[nend];
  int cnt = be1 - be0;
  int scnt = cnt < GCAP ? cnt : GCAP;
  for (int i = tid; i < scnt; i += 256) {
    s_src[i] = csr_src[be0 + i];
    s_nrm[i] = csr_norm[be0 + i];
  }
  __syncthreads();
  int n = nb + nl;
  if (n >= NN) return;
  const float4* xb = xw + (size_t)b * NN * 16;
  float sn = selfn[n];
  float4 v = xb[n * 16 + f4];
  float ax = v.x * sn, ay = v.y * sn, az = v.z * sn, aw = v.w * sn;
  float bx = 0.f, by = 0.f, bz = 0.f, bw = 0.f;
  int le0 = rowptr[n] - be0, le1 = rowptr[n + 1] - be0;
  int lim = le1 < GCAP ? le1 : GCAP;
  int e = le0;
  for (; e + 1 < lim; e += 2) {
    int s1 = s_src[e], s2 = s_src[e + 1];
    float w1 = s_nrm[e], w2 = s_nrm[e + 1];
    float4 u1 = xb[s1 * 16 + f4];
    float4 u2 = xb[s2 * 16 + f4];
    ax += w1 * u1.x; ay += w1 * u1.y; az += w1 * u1.z; aw += w1 * u1.w;
    bx += w2 * u2.x; by += w2 * u2.y; bz += w2 * u2.z; bw += w2 * u2.w;
  }
  if (e < lim) {
    int s1 = s_src[e];
    float w1 = s_nrm[e];
    float4 u1 = xb[s1 * 16 + f4];
    ax += w1 * u1.x; ay += w1 * u1.y; az += w1 * u1.z; aw += w1 * u1.w;
  }
  // overflow fallback (block had >GCAP edges): read tail from global
  for (e = (le0 > GCAP ? le0 : GCAP); e < le1; ++e) {
    int s1 = csr_src[be0 + e];
    float w1 = csr_norm[be0 + e];
    float4 u1 = xb[s1 * 16 + f4];
    ax += w1 * u1.x; ay += w1 * u1.y; az += w1 * u1.z; aw += w1 * u1.w;
  }
  float4 bb = ((const float4*)bias)[f4];
  float4 o = make_float4(ax + bx + bb.x, ay + by + bb.y, az + bz + bb.z, aw + bw + bb.w);
  outg[((size_t)(b0 + b) * NN + n) * 16 + f4] = o;
}

// ---------------- RNN: per-node-independent recurrence ----------------
// block = 5 nodes x 50 hidden dims (250 active lanes of 256); loops all 128 steps.
// Weights live in NATIVE float4/float2 local arrays (constant unrolled indices
// -> SROA keeps them in VGPRs; the round-2 version's reinterpret-casts forced
// them to memory: VGPR_Count=76 and per-step reloads). 4 accumulators for ILP.
__global__ __launch_bounds__(256, 3) void rnn_kernel(const float* __restrict__ x,
    const float* __restrict__ Wih, const float* __restrict__ Whh,
    const float* __restrict__ bih, const float* __restrict__ bhh,
    const float* __restrict__ h0, float* __restrict__ out) {
  __shared__ float xs[5 * 64];
  __shared__ float hs[5 * 52];
  int tid = threadIdx.x;
  int n0 = blockIdx.x * 5;
  int nl = tid / 50;
  int j = tid - nl * 50;
  bool active = tid < 250;
  int jj = active ? j : 0;  // inactive lanes read row 0 (valid memory, result unused)
  float4 wih4[16];
  float2 whh2[25];
  const float4* wihp = (const float4*)(Wih + jj * 64);   // 256B-aligned
  const float2* whhp = (const float2*)(Whh + jj * 50);   // 8B-aligned
#pragma unroll
  for (int q = 0; q < 16; ++q) wih4[q] = wihp[q];
#pragma unroll
  for (int q = 0; q < 25; ++q) whh2[q] = whhp[q];
  float bj = bih[jj] + bhh[jj];
  if (tid < 5 * 52) hs[tid] = 0.f;  // zero pad lanes 50/51 per node
  __syncthreads();
  if (active) hs[nl * 52 + j] = h0[n0 * 50 + tid];  // n*50+j == tid for packed layout
  const size_t NX = (size_t)NN * 64;
  const size_t NOUT = (size_t)NN * 50;
  float4 xpre = make_float4(0.f, 0.f, 0.f, 0.f);
  if (tid < 80) xpre = ((const float4*)x)[n0 * 16 + tid];
  for (int t = 0; t < NB; ++t) {
    if (tid < 80) ((float4*)xs)[tid] = xpre;
    __syncthreads();  // xs staged; hs writes from t-1 visible
    if (t + 1 < NB && tid < 80)
      xpre = ((const float4*)(x + (size_t)(t + 1) * NX))[n0 * 16 + tid];  // prefetch next step
    float a0 = bj, a1 = 0.f, a2 = 0.f, a3 = 0.f;
    const float4* xr = (const float4*)&xs[nl * 64];      // 256B-aligned in LDS
    const float2* hr = (const float2*)&hs[nl * 52];      // 8B-aligned in LDS
#pragma unroll
    for (int q = 0; q < 16; q += 4) {
      float4 x0 = xr[q], x1 = xr[q + 1], x2 = xr[q + 2], x3 = xr[q + 3];
      a0 += x0.x * wih4[q].x + x0.y * wih4[q].y + x0.z * wih4[q].z + x0.w * wih4[q].w;
      a1 += x1.x * wih4[q + 1].x + x1.y * wih4[q + 1].y + x1.z * wih4[q + 1].z + x1.w * wih4[q + 1].w;
      a2 += x2.x * wih4[q + 2].x + x2.y * wih4[q + 2].y + x2.z * wih4[q + 2].z + x2.w * wih4[q + 2].w;
      a3 += x3.x * wih4[q + 3].x + x3.y * wih4[q + 3].y + x3.z * wih4[q + 3].z + x3.w * wih4[q + 3].w;
    }
#pragma unroll
    for (int q = 0; q < 24; q += 4) {
      float2 h0v = hr[q], h1v = hr[q + 1], h2v = hr[q + 2], h3v = hr[q + 3];
      a0 += h0v.x * whh2[q].x + h0v.y * whh2[q].y;
      a1 += h1v.x * whh2[q + 1].x + h1v.y * whh2[q + 1].y;
      a2 += h2v.x * whh2[q + 2].x + h2v.y * whh2[q + 2].y;
      a3 += h3v.x * whh2[q + 3].x + h3v.y * whh2[q + 3].y;
    }
    {
      float2 h24 = hr[24];
      a0 += h24.x * whh2[24].x + h24.y * whh2[24].y;
    }
    float hnew = tanhf(((a0 + a1) + (a2 + a3)));
    __syncthreads();  // all hs reads done
    if (active) {
      hs[nl * 52 + j] = hnew;
      out[(size_t)t * NOUT + n0 * 50 + tid] = hnew;  // contiguous 250 floats/block
    }
  }
}

// ---------------- host ----------------

extern "C" void kernel_launch(void* const* d_in, const int* in_sizes, int n_in,
                              void* d_out, int out_size, void* d_ws, size_t ws_size,
                              hipStream_t stream) {
  const float* x_in = (const float*)d_in[0];
  const int* ei     = (const int*)d_in[1];
  const float* ew   = (const float*)d_in[2];
  const float* W    = (const float*)d_in[3];
  const float* bias = (const float*)d_in[4];
  const float* Wih  = (const float*)d_in[5];
  const float* Whh  = (const float*)d_in[6];
  const float* bih  = (const float*)d_in[7];
  const float* bhh  = (const float*)d_in[8];
  const float* h0   = (const float*)d_in[9];
  float* out = (float*)d_out;

  char* ws = (char*)d_ws;
  size_t off = 0;
  auto alloc = [&](size_t bytes) {
    size_t o = off;
    off += (bytes + 255) & ~(size_t)255;
    return o;
  };
  float* xw    = (float*)(ws + alloc((size_t)MCH * NO * 4));          // 25.1 MB (per-chunk)
  float* gcn   = (float*)(ws + alloc((size_t)NB * NN * NO * 4));      // 100.6 MB
  int*   zb    = (int*)(ws + alloc((size_t)4 * NN * 4));              // zeroed each call
  int* mark = zb;
  int* degc = zb + NN;
  float* degw = (float*)(zb + 2 * NN);
  int* cursor = zb + 3 * NN;
  int*   ranks  = (int*)(ws + alloc(NN * 4));
  int*   srcr   = (int*)(ws + alloc(NE * 4));
  int*   dstr   = (int*)(ws + alloc(NE * 4));
  float* dinv   = (float*)(ws + alloc(NN * 4));
  float* selfn  = (float*)(ws + alloc(NN * 4));
  int*   rowptr = (int*)(ws + alloc((NN + 1) * 4));
  int*   csrc   = (int*)(ws + alloc(NE * 4));
  float* cnorm  = (float*)(ws + alloc(NE * 4));

  zero_kernel<<<(4 * NN + 255) / 256, 256, 0, stream>>>(zb, 4 * NN);
  mark_kernel<<<(2 * NE + 255) / 256, 256, 0, stream>>>(ei, mark);
  exscan_kernel<<<1, 1024, 0, stream>>>(mark, ranks, NN, 0);
  remap_deg_kernel<<<(NE + 255) / 256, 256, 0, stream>>>(ei, ew, ranks, srcr, dstr, degc, degw);
  dinv_kernel<<<(NN + 255) / 256, 256, 0, stream>>>(degw, dinv, selfn);
  exscan_kernel<<<1, 1024, 0, stream>>>(degc, rowptr, NN, 1);
  csr_fill_kernel<<<(NE + 255) / 256, 256, 0, stream>>>(ew, srcr, dstr, rowptr, cursor, dinv, csrc, cnorm);

  for (int c = 0; c < NCHUNK; ++c) {
    gemm_kernel<<<(MCH + 127) / 128, 256, 0, stream>>>(
        x_in + (size_t)c * MCH * NF, W, xw, MCH);
    dim3 gg((NN + 15) / 16, BCH);
    gather_kernel<<<gg, 256, 0, stream>>>(
        (const float4*)xw, rowptr, csrc, cnorm, selfn, bias, (float4*)gcn, c * BCH);
  }
  rnn_kernel<<<NN / 5, 256, 0, stream>>>(gcn, Wih, Whh, bih, bhh, h0, out);
}

// Round 4
// 617.970 us; speedup vs baseline: 1.2539x; 1.2539x over previous
//
#include <hip/hip_runtime.h>

#define NN 3070      // nodes
#define NF 128       // in features
#define NO 64        // gcn out features (pre-fold)
#define NH 50        // hidden
#define NC 52        // stored cols after W_ih fold (50 + 2 pad)
#define NE 49120     // edges
#define NB 128       // batch (= rnn seq len)
#define BCH 32       // batches per chunk
#define NCHUNK 4
#define MCH (BCH * NN)   // 98240 rows per gemm chunk
#define GCAP 1024        // staged edges per 16-node gather block

// ---------------- edge preprocessing ----------------

__global__ __launch_bounds__(256) void zero_kernel(int* __restrict__ p, int n) {
  int i = blockIdx.x * 256 + threadIdx.x;
  if (i < n) p[i] = 0;
}

__global__ __launch_bounds__(256) void mark_kernel(const int* __restrict__ ei, int* __restrict__ mark) {
  int i = blockIdx.x * 256 + threadIdx.x;
  if (i < 2 * NE) mark[ei[i]] = 1;
}

// exclusive prefix scan of n<=3072 ints, single block of 1024 threads, 3 items/thread
__global__ __launch_bounds__(1024) void exscan_kernel(const int* __restrict__ in, int* __restrict__ out,
                                                      int n, int write_total) {
  __shared__ int part[1024];
  int tid = threadIdx.x;
  int base = tid * 3;
  int v0 = (base + 0 < n) ? in[base + 0] : 0;
  int v1 = (base + 1 < n) ? in[base + 1] : 0;
  int v2 = (base + 2 < n) ? in[base + 2] : 0;
  int s = v0 + v1 + v2;
  part[tid] = s;
  __syncthreads();
  for (int off = 1; off < 1024; off <<= 1) {
    int t = (tid >= off) ? part[tid - off] : 0;
    __syncthreads();
    part[tid] += t;
    __syncthreads();
  }
  int run = part[tid] - s;  // exclusive base of this thread's chunk
  if (base + 0 < n) out[base + 0] = run; run += v0;
  if (base + 1 < n) out[base + 1] = run; run += v1;
  if (base + 2 < n) out[base + 2] = run;
  if (write_total && tid == 1023) out[n] = part[1023];
}

__global__ __launch_bounds__(256) void remap_deg_kernel(const int* __restrict__ ei, const float* __restrict__ ew,
    const int* __restrict__ ranks, int* __restrict__ srcr, int* __restrict__ dstr,
    int* __restrict__ degc, float* __restrict__ degw) {
  int e = blockIdx.x * 256 + threadIdx.x;
  if (e >= NE) return;
  int s = ranks[ei[e]];
  int d = ranks[ei[NE + e]];
  srcr[e] = s;
  dstr[e] = d;
  atomicAdd(&degc[d], 1);
  atomicAdd(&degw[d], ew[e]);
}

__global__ __launch_bounds__(256) void dinv_kernel(const float* __restrict__ degw,
    float* __restrict__ dinv, float* __restrict__ selfn) {
  int n = blockIdx.x * 256 + threadIdx.x;
  if (n >= NN) return;
  float dg = degw[n] + 1.0f;  // + self-loop weight 1
  float di = rsqrtf(dg);      // dg >= 1 always
  dinv[n] = di;
  selfn[n] = di * di;         // self-loop message norm
}

__global__ __launch_bounds__(256) void csr_fill_kernel(const float* __restrict__ ew, const int* __restrict__ srcr,
    const int* __restrict__ dstr, const int* __restrict__ rowptr, int* __restrict__ cursor,
    const float* __restrict__ dinv, int* __restrict__ csr_src, float* __restrict__ csr_norm) {
  int e = blockIdx.x * 256 + threadIdx.x;
  if (e >= NE) return;
  int d = dstr[e];
  int s = srcr[e];
  int pos = rowptr[d] + atomicAdd(&cursor[d], 1);
  csr_src[pos] = s;
  csr_norm[pos] = dinv[s] * ew[e] * dinv[d];
}

// ---------------- fold W_ih into GCN: W' = W @ W_ih^T (128x50, pad to 64) ----
// b' = b @ W_ih^T + b_ih + b_hh  (52, pad 0). One-shot tiny kernel.
__global__ __launch_bounds__(256) void wfold_kernel(const float* __restrict__ W,
    const float* __restrict__ Wih, const float* __restrict__ b,
    const float* __restrict__ bih, const float* __restrict__ bhh,
    float* __restrict__ Wp, float* __restrict__ bp) {
  int idx = blockIdx.x * 256 + threadIdx.x;
  if (idx < 128 * 64) {
    int k = idx >> 6, j = idx & 63;
    float s = 0.f;
    if (j < NH) {
      for (int o = 0; o < NO; ++o) s += W[k * NO + o] * Wih[j * NO + o];
    }
    Wp[k * 64 + j] = s;
  }
  if (idx < NC) {
    float s = 0.f;
    if (idx < NH) {
      for (int o = 0; o < NO; ++o) s += b[o] * Wih[idx * NO + o];
      s += bih[idx] + bhh[idx];
    }
    bp[idx] = s;
  }
}

// ---------------- GEMM: xw = A(M,128) @ Wp(128,64), store cols 0..51, stride 52
__global__ __launch_bounds__(256) void gemm_kernel(const float* __restrict__ A,
    const float* __restrict__ W, float* __restrict__ out, int M) {
  __shared__ float As[128 * 68];   // [row][k], stride 68 -> 2-way reads (free)
  __shared__ float Ws[32 * 64];    // [k][col], broadcast reads
  int tid = threadIdx.x;
  int row0 = blockIdx.x * 128;
  int rg = tid >> 3;        // 0..31 : rows rg + 32*i
  int cg = tid & 7;         // cols cg*8 .. cg*8+7
  int c0 = cg * 8;
  float acc[4][8];
#pragma unroll
  for (int i = 0; i < 4; ++i)
#pragma unroll
    for (int j = 0; j < 8; ++j) acc[i][j] = 0.f;

  for (int kc = 0; kc < 4; ++kc) {
#pragma unroll
    for (int j = 0; j < 4; ++j) {
      int f = tid + 256 * j;        // 0..1023
      int r = f >> 3, kq = f & 7;
      int grow = row0 + r;
      float4 v = make_float4(0.f, 0.f, 0.f, 0.f);
      if (grow < M) v = *(const float4*)&A[(size_t)grow * NF + kc * 32 + kq * 4];
      *(float4*)&As[r * 68 + kq * 4] = v;
    }
#pragma unroll
    for (int j = 0; j < 2; ++j) {
      int f = tid + 256 * j;        // 0..511
      int kk = f >> 4, cq = f & 15;
      *(float4*)&Ws[kk * 64 + cq * 4] = *(const float4*)&W[(size_t)(kc * 32 + kk) * 64 + cq * 4];
    }
    __syncthreads();
#pragma unroll 2
    for (int k4 = 0; k4 < 32; k4 += 4) {
      float4 a[4];
#pragma unroll
      for (int i = 0; i < 4; ++i) a[i] = *(const float4*)&As[(rg + 32 * i) * 68 + k4];
#pragma unroll
      for (int m = 0; m < 4; ++m) {
        float4 w0 = *(const float4*)&Ws[(k4 + m) * 64 + c0];
        float4 w1 = *(const float4*)&Ws[(k4 + m) * 64 + c0 + 4];
#pragma unroll
        for (int i = 0; i < 4; ++i) {
          float av = (m == 0) ? a[i].x : (m == 1) ? a[i].y : (m == 2) ? a[i].z : a[i].w;
          acc[i][0] += av * w0.x; acc[i][1] += av * w0.y;
          acc[i][2] += av * w0.z; acc[i][3] += av * w0.w;
          acc[i][4] += av * w1.x; acc[i][5] += av * w1.y;
          acc[i][6] += av * w1.z; acc[i][7] += av * w1.w;
        }
      }
    }
    __syncthreads();
  }
#pragma unroll
  for (int i = 0; i < 4; ++i) {
    int r = row0 + rg + 32 * i;
    if (r < M) {
      if (c0 < NC)                 // c0<=48: cols c0..c0+3 valid
        *(float4*)&out[(size_t)r * NC + c0] = make_float4(acc[i][0], acc[i][1], acc[i][2], acc[i][3]);
      if (c0 + 4 < NC)             // c0<=40: cols c0+4..c0+7 valid
        *(float4*)&out[(size_t)r * NC + c0 + 4] = make_float4(acc[i][4], acc[i][5], acc[i][6], acc[i][7]);
    }
  }
}

// ---------------- GCN aggregation: atomic-free CSR gather (52-col) ----------
// Block = 16 nodes x 13 float4-feats (f4<13 active of 16); grid.y = batch.
__global__ __launch_bounds__(256) void gather_kernel(const float4* __restrict__ xw,
    const int* __restrict__ rowptr, const int* __restrict__ csr_src, const float* __restrict__ csr_norm,
    const float* __restrict__ selfn, const float* __restrict__ bp, float4* __restrict__ outg, int b0) {
  __shared__ int s_src[GCAP];
  __shared__ float s_nrm[GCAP];
  int tid = threadIdx.x;
  int f4 = tid & 15, nl = tid >> 4;
  int nb = blockIdx.x * 16;
  int b = blockIdx.y;
  int nend = nb + 16 < NN ? nb + 16 : NN;
  int be0 = rowptr[nb], be1 = rowptr[nend];
  int cnt = be1 - be0;
  int scnt = cnt < GCAP ? cnt : GCAP;
  for (int i = tid; i < scnt; i += 256) {
    s_src[i] = csr_src[be0 + i];
    s_nrm[i] = csr_norm[be0 + i];
  }
  __syncthreads();
  int n = nb + nl;
  if (n >= NN || f4 >= 13) return;
  const float4* xb = xw + (size_t)b * NN * 13;
  float sn = selfn[n];
  float4 v = xb[n * 13 + f4];
  float ax = v.x * sn, ay = v.y * sn, az = v.z * sn, aw = v.w * sn;
  float bx = 0.f, by = 0.f, bz = 0.f, bw = 0.f;
  int le0 = rowptr[n] - be0, le1 = rowptr[n + 1] - be0;
  int lim = le1 < GCAP ? le1 : GCAP;
  int e = le0;
  for (; e + 1 < lim; e += 2) {
    int s1 = s_src[e], s2 = s_src[e + 1];
    float w1 = s_nrm[e], w2 = s_nrm[e + 1];
    float4 u1 = xb[s1 * 13 + f4];
    float4 u2 = xb[s2 * 13 + f4];
    ax += w1 * u1.x; ay += w1 * u1.y; az += w1 * u1.z; aw += w1 * u1.w;
    bx += w2 * u2.x; by += w2 * u2.y; bz += w2 * u2.z; bw += w2 * u2.w;
  }
  if (e < lim) {
    int s1 = s_src[e];
    float w1 = s_nrm[e];
    float4 u1 = xb[s1 * 13 + f4];
    ax += w1 * u1.x; ay += w1 * u1.y; az += w1 * u1.z; aw += w1 * u1.w;
  }
  for (e = (le0 > GCAP ? le0 : GCAP); e < le1; ++e) {   // overflow tail
    int s1 = csr_src[be0 + e];
    float w1 = csr_norm[be0 + e];
    float4 u1 = xb[s1 * 13 + f4];
    ax += w1 * u1.x; ay += w1 * u1.y; az += w1 * u1.z; aw += w1 * u1.w;
  }
  float4 bb = ((const float4*)bp)[f4];
  float4 o = make_float4(ax + bx + bb.x, ay + by + bb.y, az + bz + bb.z, aw + bw + bb.w);
  outg[((size_t)(b0 + b) * NN + n) * 13 + f4] = o;
}

// ---------------- RNN: h = tanh(pre + W_hh h), input term pre-folded --------
// block = 5 nodes x 50 j (250/256 lanes); 128 steps; whh row = 25 float2 regs.
// tanh inlined via v_exp_f32 + v_rcp (no libcall -> no forced spills).
__global__ __launch_bounds__(256, 3) void rnn_kernel(const float* __restrict__ pre,
    const float* __restrict__ Whh, const float* __restrict__ h0, float* __restrict__ out) {
  __shared__ float hs[6 * 52];   // row 5 = scratch for inactive lanes
  int tid = threadIdx.x;
  int n0 = blockIdx.x * 5;
  int nl = tid / 50;
  int j = tid - nl * 50;
  bool active = tid < 250;
  int jj = active ? j : 0;
  float2 whh2[25];
  const float2* whhp = (const float2*)(Whh + jj * NH);
#pragma unroll
  for (int q = 0; q < 25; ++q) whh2[q] = whhp[q];
  if (tid < 6 * 52) hs[tid] = 0.f;
  if (tid + 256 < 6 * 52) hs[tid + 256] = 0.f;
  __syncthreads();
  if (active) hs[nl * 52 + j] = h0[n0 * 50 + tid];
  const size_t NPRE = (size_t)NN * NC;
  const size_t NOUT = (size_t)NN * NH;
  int nn = active ? (n0 + nl) : n0;
  const float* prep = pre + (size_t)nn * NC + jj;
  float xpre = prep[0];
  __syncthreads();
  for (int t = 0; t < NB; ++t) {
    float a0 = xpre, a1 = 0.f, a2 = 0.f, a3 = 0.f;
    if (t + 1 < NB) xpre = prep[(size_t)(t + 1) * NPRE];  // prefetch next step
    const float4* hr = (const float4*)&hs[nl * 52];       // 208B-aligned
#pragma unroll
    for (int q = 0; q < 12; q += 4) {
      float4 h0v = hr[q], h1v = hr[q + 1], h2v = hr[q + 2], h3v = hr[q + 3];
      a0 += h0v.x * whh2[2*q].x   + h0v.y * whh2[2*q].y   + h0v.z * whh2[2*q+1].x + h0v.w * whh2[2*q+1].y;
      a1 += h1v.x * whh2[2*q+2].x + h1v.y * whh2[2*q+2].y + h1v.z * whh2[2*q+3].x + h1v.w * whh2[2*q+3].y;
      a2 += h2v.x * whh2[2*q+4].x + h2v.y * whh2[2*q+4].y + h2v.z * whh2[2*q+5].x + h2v.w * whh2[2*q+5].y;
      a3 += h3v.x * whh2[2*q+6].x + h3v.y * whh2[2*q+6].y + h3v.z * whh2[2*q+7].x + h3v.w * whh2[2*q+7].y;
    }
    {
      float2 ht = *(const float2*)&hs[nl * 52 + 48];
      a0 += ht.x * whh2[24].x + ht.y * whh2[24].y;
    }
    float v = (a0 + a1) + (a2 + a3);
    float e = __expf(-2.f * fabsf(v));
    float r = (1.f - e) * __builtin_amdgcn_rcpf(1.f + e);
    float hnew = (v < 0.f) ? -r : r;
    __syncthreads();  // all hs reads done
    if (active) {
      hs[nl * 52 + j] = hnew;
      out[(size_t)t * NOUT + n0 * 50 + tid] = hnew;  // contiguous 250 floats/block
    }
    __syncthreads();  // hs writes visible
  }
}

// ---------------- host ----------------

extern "C" void kernel_launch(void* const* d_in, const int* in_sizes, int n_in,
                              void* d_out, int out_size, void* d_ws, size_t ws_size,
                              hipStream_t stream) {
  const float* x_in = (const float*)d_in[0];
  const int* ei     = (const int*)d_in[1];
  const float* ew   = (const float*)d_in[2];
  const float* W    = (const float*)d_in[3];
  const float* bias = (const float*)d_in[4];
  const float* Wih  = (const float*)d_in[5];
  const float* Whh  = (const float*)d_in[6];
  const float* bih  = (const float*)d_in[7];
  const float* bhh  = (const float*)d_in[8];
  const float* h0   = (const float*)d_in[9];
  float* out = (float*)d_out;

  char* ws = (char*)d_ws;
  size_t off = 0;
  auto alloc = [&](size_t bytes) {
    size_t o = off;
    off += (bytes + 255) & ~(size_t)255;
    return o;
  };
  float* xw    = (float*)(ws + alloc((size_t)MCH * NC * 4));          // 20.4 MB (per-chunk)
  float* gcn   = (float*)(ws + alloc((size_t)NB * NN * NC * 4));      // 81.7 MB
  int*   zb    = (int*)(ws + alloc((size_t)4 * NN * 4));              // zeroed each call
  int* mark = zb;
  int* degc = zb + NN;
  float* degw = (float*)(zb + 2 * NN);
  int* cursor = zb + 3 * NN;
  int*   ranks  = (int*)(ws + alloc(NN * 4));
  int*   srcr   = (int*)(ws + alloc(NE * 4));
  int*   dstr   = (int*)(ws + alloc(NE * 4));
  float* dinv   = (float*)(ws + alloc(NN * 4));
  float* selfn  = (float*)(ws + alloc(NN * 4));
  int*   rowptr = (int*)(ws + alloc((NN + 1) * 4));
  int*   csrc   = (int*)(ws + alloc(NE * 4));
  float* cnorm  = (float*)(ws + alloc(NE * 4));
  float* Wp     = (float*)(ws + alloc(128 * 64 * 4));
  float* bp     = (float*)(ws + alloc(NC * 4));

  zero_kernel<<<(4 * NN + 255) / 256, 256, 0, stream>>>(zb, 4 * NN);
  mark_kernel<<<(2 * NE + 255) / 256, 256, 0, stream>>>(ei, mark);
  exscan_kernel<<<1, 1024, 0, stream>>>(mark, ranks, NN, 0);
  remap_deg_kernel<<<(NE + 255) / 256, 256, 0, stream>>>(ei, ew, ranks, srcr, dstr, degc, degw);
  dinv_kernel<<<(NN + 255) / 256, 256, 0, stream>>>(degw, dinv, selfn);
  exscan_kernel<<<1, 1024, 0, stream>>>(degc, rowptr, NN, 1);
  csr_fill_kernel<<<(NE + 255) / 256, 256, 0, stream>>>(ew, srcr, dstr, rowptr, cursor, dinv, csrc, cnorm);
  wfold_kernel<<<32, 256, 0, stream>>>(W, Wih, bias, bih, bhh, Wp, bp);

  for (int c = 0; c < NCHUNK; ++c) {
    gemm_kernel<<<(MCH + 127) / 128, 256, 0, stream>>>(
        x_in + (size_t)c * MCH * NF, Wp, xw, MCH);
    dim3 gg((NN + 15) / 16, BCH);
    gather_kernel<<<gg, 256, 0, stream>>>(
        (const float4*)xw, rowptr, csrc, cnorm, selfn, bp, (float4*)gcn, c * BCH);
  }
  rnn_kernel<<<(NN + 4) / 5, 256, 0, stream>>>(gcn, Whh, h0, out);
}

// Round 5
// 575.852 us; speedup vs baseline: 1.3457x; 1.0731x over previous
//
#include <hip/hip_runtime.h>

#define NN 3070      // nodes
#define NF 128       // in features
#define NO 64        // gcn out features (pre-fold)
#define NH 50        // hidden
#define NC 52        // stored cols after W_ih fold (50 + 2 pad)
#define NE 49120     // edges
#define NB 128       // batch (= rnn seq len)
#define MTOT (NB * NN)   // 392960 rows, = 256 * 1535 exactly
#define GCAP 1024        // staged edges per 16-node gather block

// ---------------- edge preprocessing ----------------

__global__ __launch_bounds__(256) void zero_kernel(int* __restrict__ p, int n) {
  int i = blockIdx.x * 256 + threadIdx.x;
  if (i < n) p[i] = 0;
}

__global__ __launch_bounds__(256) void mark_kernel(const int* __restrict__ ei, int* __restrict__ mark) {
  int i = blockIdx.x * 256 + threadIdx.x;
  if (i < 2 * NE) mark[ei[i]] = 1;
}

// exclusive prefix scan of n<=3072 ints, single block of 1024 threads, 3 items/thread
__global__ __launch_bounds__(1024) void exscan_kernel(const int* __restrict__ in, int* __restrict__ out,
                                                      int n, int write_total) {
  __shared__ int part[1024];
  int tid = threadIdx.x;
  int base = tid * 3;
  int v0 = (base + 0 < n) ? in[base + 0] : 0;
  int v1 = (base + 1 < n) ? in[base + 1] : 0;
  int v2 = (base + 2 < n) ? in[base + 2] : 0;
  int s = v0 + v1 + v2;
  part[tid] = s;
  __syncthreads();
  for (int off = 1; off < 1024; off <<= 1) {
    int t = (tid >= off) ? part[tid - off] : 0;
    __syncthreads();
    part[tid] += t;
    __syncthreads();
  }
  int run = part[tid] - s;  // exclusive base of this thread's chunk
  if (base + 0 < n) out[base + 0] = run; run += v0;
  if (base + 1 < n) out[base + 1] = run; run += v1;
  if (base + 2 < n) out[base + 2] = run;
  if (write_total && tid == 1023) out[n] = part[1023];
}

__global__ __launch_bounds__(256) void remap_deg_kernel(const int* __restrict__ ei, const float* __restrict__ ew,
    const int* __restrict__ ranks, int* __restrict__ srcr, int* __restrict__ dstr,
    int* __restrict__ degc, float* __restrict__ degw) {
  int e = blockIdx.x * 256 + threadIdx.x;
  if (e >= NE) return;
  int s = ranks[ei[e]];
  int d = ranks[ei[NE + e]];
  srcr[e] = s;
  dstr[e] = d;
  atomicAdd(&degc[d], 1);
  atomicAdd(&degw[d], ew[e]);
}

__global__ __launch_bounds__(256) void dinv_kernel(const float* __restrict__ degw,
    float* __restrict__ dinv, float* __restrict__ selfn) {
  int n = blockIdx.x * 256 + threadIdx.x;
  if (n >= NN) return;
  float dg = degw[n] + 1.0f;  // + self-loop weight 1
  float di = rsqrtf(dg);      // dg >= 1 always
  dinv[n] = di;
  selfn[n] = di * di;         // self-loop message norm
}

__global__ __launch_bounds__(256) void csr_fill_kernel(const float* __restrict__ ew, const int* __restrict__ srcr,
    const int* __restrict__ dstr, const int* __restrict__ rowptr, int* __restrict__ cursor,
    const float* __restrict__ dinv, int* __restrict__ csr_src, float* __restrict__ csr_norm) {
  int e = blockIdx.x * 256 + threadIdx.x;
  if (e >= NE) return;
  int d = dstr[e];
  int s = srcr[e];
  int pos = rowptr[d] + atomicAdd(&cursor[d], 1);
  csr_src[pos] = s;
  csr_norm[pos] = dinv[s] * ew[e] * dinv[d];
}

// ---------------- fold W_ih into GCN: W' = W @ W_ih^T (128x50, pad to 64) ----
// b' = b @ W_ih^T + b_ih + b_hh  (52, pad 0). One-shot tiny kernel.
__global__ __launch_bounds__(256) void wfold_kernel(const float* __restrict__ W,
    const float* __restrict__ Wih, const float* __restrict__ b,
    const float* __restrict__ bih, const float* __restrict__ bhh,
    float* __restrict__ Wp, float* __restrict__ bp) {
  int idx = blockIdx.x * 256 + threadIdx.x;
  if (idx < 128 * 64) {
    int k = idx >> 6, j = idx & 63;
    float s = 0.f;
    if (j < NH) {
      for (int o = 0; o < NO; ++o) s += W[k * NO + o] * Wih[j * NO + o];
    }
    Wp[k * 64 + j] = s;
  }
  if (idx < NC) {
    float s = 0.f;
    if (idx < NH) {
      for (int o = 0; o < NO; ++o) s += b[o] * Wih[idx * NO + o];
      s += bih[idx] + bhh[idx];
    }
    bp[idx] = s;
  }
}

// ---------------- GEMM: xw = A(392960,128) @ Wp(128,64), store cols 0..51 ----
// 256-row tile/block (1535 blocks exact), 256 threads, micro-tile 8x8
// (acc=64 VGPRs, 2.0 LDS-FLOP/byte). K chunked by 32. LDS 45KB -> 3 blocks/CU.
// A-tile stride 36: compute reads (4*rg+k4)%32 conflict-free; staging 2-way (free).
__global__ __launch_bounds__(256, 3) void gemm_kernel(const float* __restrict__ A,
    const float* __restrict__ W, float* __restrict__ out) {
  __shared__ float As[256 * 36];   // 36864 B
  __shared__ float Ws[32 * 64];    // 8192 B
  int tid = threadIdx.x;
  int row0 = blockIdx.x * 256;
  int rg = tid >> 3;        // 0..31 : rows rg + 32*i
  int cg = tid & 7;         // cols cg*8 .. cg*8+7
  int c0 = cg * 8;
  float acc[8][8];
#pragma unroll
  for (int i = 0; i < 8; ++i)
#pragma unroll
    for (int j = 0; j < 8; ++j) acc[i][j] = 0.f;

  for (int kc = 0; kc < 4; ++kc) {
    // stage A chunk: 256 rows x 32 k (8 float4 / thread)
#pragma unroll
    for (int j = 0; j < 8; ++j) {
      int f = tid + 256 * j;        // 0..2047
      int r = f >> 3, kq = f & 7;
      float4 v = *(const float4*)&A[(size_t)(row0 + r) * NF + kc * 32 + kq * 4];
      *(float4*)&As[r * 36 + kq * 4] = v;
    }
    // stage W chunk: 32 k x 64 cols (2 float4 / thread)
#pragma unroll
    for (int j = 0; j < 2; ++j) {
      int f = tid + 256 * j;        // 0..511
      int kk = f >> 4, cq = f & 15;
      *(float4*)&Ws[kk * 64 + cq * 4] = *(const float4*)&W[(size_t)(kc * 32 + kk) * 64 + cq * 4];
    }
    __syncthreads();
#pragma unroll 2
    for (int k4 = 0; k4 < 32; k4 += 4) {
      float4 a[8];
#pragma unroll
      for (int i = 0; i < 8; ++i) a[i] = *(const float4*)&As[(rg + 32 * i) * 36 + k4];
#pragma unroll
      for (int m = 0; m < 4; ++m) {
        float4 w0 = *(const float4*)&Ws[(k4 + m) * 64 + c0];
        float4 w1 = *(const float4*)&Ws[(k4 + m) * 64 + c0 + 4];
#pragma unroll
        for (int i = 0; i < 8; ++i) {
          float av = (m == 0) ? a[i].x : (m == 1) ? a[i].y : (m == 2) ? a[i].z : a[i].w;
          acc[i][0] += av * w0.x; acc[i][1] += av * w0.y;
          acc[i][2] += av * w0.z; acc[i][3] += av * w0.w;
          acc[i][4] += av * w1.x; acc[i][5] += av * w1.y;
          acc[i][6] += av * w1.z; acc[i][7] += av * w1.w;
        }
      }
    }
    __syncthreads();
  }
#pragma unroll
  for (int i = 0; i < 8; ++i) {
    size_t r = row0 + rg + 32 * i;
    if (c0 < NC)                 // cg<=6: cols c0..c0+3 valid (cg==6 -> 48..51)
      *(float4*)&out[r * NC + c0] = make_float4(acc[i][0], acc[i][1], acc[i][2], acc[i][3]);
    if (c0 + 4 < NC)             // cg<=5: cols c0+4..c0+7 valid
      *(float4*)&out[r * NC + c0 + 4] = make_float4(acc[i][4], acc[i][5], acc[i][6], acc[i][7]);
  }
}

// ---------------- GCN aggregation: atomic-free CSR gather (52-col) ----------
// Block = 16 nodes x 13 float4-feats (f4<13 active of 16); grid.y = batch (128).
__global__ __launch_bounds__(256) void gather_kernel(const float4* __restrict__ xw,
    const int* __restrict__ rowptr, const int* __restrict__ csr_src, const float* __restrict__ csr_norm,
    const float* __restrict__ selfn, const float* __restrict__ bp, float4* __restrict__ outg) {
  __shared__ int s_src[GCAP];
  __shared__ float s_nrm[GCAP];
  int tid = threadIdx.x;
  int f4 = tid & 15, nl = tid >> 4;
  int nb = blockIdx.x * 16;
  int b = blockIdx.y;
  int nend = nb + 16 < NN ? nb + 16 : NN;
  int be0 = rowptr[nb], be1 = rowptr[nend];
  int cnt = be1 - be0;
  int scnt = cnt < GCAP ? cnt : GCAP;
  for (int i = tid; i < scnt; i += 256) {
    s_src[i] = csr_src[be0 + i];
    s_nrm[i] = csr_norm[be0 + i];
  }
  __syncthreads();
  int n = nb + nl;
  if (n >= NN || f4 >= 13) return;
  const float4* xb = xw + (size_t)b * NN * 13;
  float sn = selfn[n];
  float4 v = xb[n * 13 + f4];
  float ax = v.x * sn, ay = v.y * sn, az = v.z * sn, aw = v.w * sn;
  float bx = 0.f, by = 0.f, bz = 0.f, bw = 0.f;
  int le0 = rowptr[n] - be0, le1 = rowptr[n + 1] - be0;
  int lim = le1 < GCAP ? le1 : GCAP;
  int e = le0;
  for (; e + 1 < lim; e += 2) {
    int s1 = s_src[e], s2 = s_src[e + 1];
    float w1 = s_nrm[e], w2 = s_nrm[e + 1];
    float4 u1 = xb[s1 * 13 + f4];
    float4 u2 = xb[s2 * 13 + f4];
    ax += w1 * u1.x; ay += w1 * u1.y; az += w1 * u1.z; aw += w1 * u1.w;
    bx += w2 * u2.x; by += w2 * u2.y; bz += w2 * u2.z; bw += w2 * u2.w;
  }
  if (e < lim) {
    int s1 = s_src[e];
    float w1 = s_nrm[e];
    float4 u1 = xb[s1 * 13 + f4];
    ax += w1 * u1.x; ay += w1 * u1.y; az += w1 * u1.z; aw += w1 * u1.w;
  }
  for (e = (le0 > GCAP ? le0 : GCAP); e < le1; ++e) {   // overflow tail
    int s1 = csr_src[be0 + e];
    float w1 = csr_norm[be0 + e];
    float4 u1 = xb[s1 * 13 + f4];
    ax += w1 * u1.x; ay += w1 * u1.y; az += w1 * u1.z; aw += w1 * u1.w;
  }
  float4 bb = ((const float4*)bp)[f4];
  float4 o = make_float4(ax + bx + bb.x, ay + by + bb.y, az + bz + bb.z, aw + bw + bb.w);
  outg[((size_t)b * NN + n) * 13 + f4] = o;
}

// ---------------- RNN: h = tanh(pre + W_hh h), input term pre-folded --------
// block = 5 nodes x 50 j (250/256 lanes); 128 steps; whh row = 25 float2 regs.
// tanh inlined via __expf + rcp (no libcall -> no forced spills).
__global__ __launch_bounds__(256, 3) void rnn_kernel(const float* __restrict__ pre,
    const float* __restrict__ Whh, const float* __restrict__ h0, float* __restrict__ out) {
  __shared__ float hs[6 * 52];   // row 5 = scratch for inactive lanes
  int tid = threadIdx.x;
  int n0 = blockIdx.x * 5;
  int nl = tid / 50;
  int j = tid - nl * 50;
  bool active = tid < 250;
  int jj = active ? j : 0;
  float2 whh2[25];
  const float2* whhp = (const float2*)(Whh + jj * NH);
#pragma unroll
  for (int q = 0; q < 25; ++q) whh2[q] = whhp[q];
  if (tid < 6 * 52) hs[tid] = 0.f;
  if (tid + 256 < 6 * 52) hs[tid + 256] = 0.f;
  __syncthreads();
  if (active) hs[nl * 52 + j] = h0[n0 * 50 + tid];
  const size_t NPRE = (size_t)NN * NC;
  const size_t NOUT = (size_t)NN * NH;
  int nn = active ? (n0 + nl) : n0;
  const float* prep = pre + (size_t)nn * NC + jj;
  float xpre = prep[0];
  __syncthreads();
  for (int t = 0; t < NB; ++t) {
    float a0 = xpre, a1 = 0.f, a2 = 0.f, a3 = 0.f;
    if (t + 1 < NB) xpre = prep[(size_t)(t + 1) * NPRE];  // prefetch next step
    const float4* hr = (const float4*)&hs[nl * 52];       // 208B-aligned
#pragma unroll
    for (int q = 0; q < 12; q += 4) {
      float4 h0v = hr[q], h1v = hr[q + 1], h2v = hr[q + 2], h3v = hr[q + 3];
      a0 += h0v.x * whh2[2*q].x   + h0v.y * whh2[2*q].y   + h0v.z * whh2[2*q+1].x + h0v.w * whh2[2*q+1].y;
      a1 += h1v.x * whh2[2*q+2].x + h1v.y * whh2[2*q+2].y + h1v.z * whh2[2*q+3].x + h1v.w * whh2[2*q+3].y;
      a2 += h2v.x * whh2[2*q+4].x + h2v.y * whh2[2*q+4].y + h2v.z * whh2[2*q+5].x + h2v.w * whh2[2*q+5].y;
      a3 += h3v.x * whh2[2*q+6].x + h3v.y * whh2[2*q+6].y + h3v.z * whh2[2*q+7].x + h3v.w * whh2[2*q+7].y;
    }
    {
      float2 ht = *(const float2*)&hs[nl * 52 + 48];
      a0 += ht.x * whh2[24].x + ht.y * whh2[24].y;
    }
    float v = (a0 + a1) + (a2 + a3);
    float e = __expf(-2.f * fabsf(v));
    float r = (1.f - e) * __builtin_amdgcn_rcpf(1.f + e);
    float hnew = (v < 0.f) ? -r : r;
    __syncthreads();  // all hs reads done
    if (active) {
      hs[nl * 52 + j] = hnew;
      out[(size_t)t * NOUT + n0 * 50 + tid] = hnew;  // contiguous 250 floats/block
    }
    __syncthreads();  // hs writes visible
  }
}

// ---------------- host ----------------

extern "C" void kernel_launch(void* const* d_in, const int* in_sizes, int n_in,
                              void* d_out, int out_size, void* d_ws, size_t ws_size,
                              hipStream_t stream) {
  const float* x_in = (const float*)d_in[0];
  const int* ei     = (const int*)d_in[1];
  const float* ew   = (const float*)d_in[2];
  const float* W    = (const float*)d_in[3];
  const float* bias = (const float*)d_in[4];
  const float* Wih  = (const float*)d_in[5];
  const float* Whh  = (const float*)d_in[6];
  const float* bih  = (const float*)d_in[7];
  const float* bhh  = (const float*)d_in[8];
  const float* h0   = (const float*)d_in[9];
  float* out = (float*)d_out;

  char* ws = (char*)d_ws;
  size_t off = 0;
  auto alloc = [&](size_t bytes) {
    size_t o = off;
    off += (bytes + 255) & ~(size_t)255;
    return o;
  };
  float* xw    = (float*)(ws + alloc((size_t)MTOT * NC * 4));         // 81.7 MB
  float* gcn   = (float*)(ws + alloc((size_t)MTOT * NC * 4));         // 81.7 MB
  int*   zb    = (int*)(ws + alloc((size_t)4 * NN * 4));              // zeroed each call
  int* mark = zb;
  int* degc = zb + NN;
  float* degw = (float*)(zb + 2 * NN);
  int* cursor = zb + 3 * NN;
  int*   ranks  = (int*)(ws + alloc(NN * 4));
  int*   srcr   = (int*)(ws + alloc(NE * 4));
  int*   dstr   = (int*)(ws + alloc(NE * 4));
  float* dinv   = (float*)(ws + alloc(NN * 4));
  float* selfn  = (float*)(ws + alloc(NN * 4));
  int*   rowptr = (int*)(ws + alloc((NN + 1) * 4));
  int*   csrc   = (int*)(ws + alloc(NE * 4));
  float* cnorm  = (float*)(ws + alloc(NE * 4));
  float* Wp     = (float*)(ws + alloc(128 * 64 * 4));
  float* bp     = (float*)(ws + alloc(NC * 4));

  zero_kernel<<<(4 * NN + 255) / 256, 256, 0, stream>>>(zb, 4 * NN);
  mark_kernel<<<(2 * NE + 255) / 256, 256, 0, stream>>>(ei, mark);
  exscan_kernel<<<1, 1024, 0, stream>>>(mark, ranks, NN, 0);
  remap_deg_kernel<<<(NE + 255) / 256, 256, 0, stream>>>(ei, ew, ranks, srcr, dstr, degc, degw);
  dinv_kernel<<<(NN + 255) / 256, 256, 0, stream>>>(degw, dinv, selfn);
  exscan_kernel<<<1, 1024, 0, stream>>>(degc, rowptr, NN, 1);
  csr_fill_kernel<<<(NE + 255) / 256, 256, 0, stream>>>(ew, srcr, dstr, rowptr, cursor, dinv, csrc, cnorm);
  wfold_kernel<<<32, 256, 0, stream>>>(W, Wih, bias, bih, bhh, Wp, bp);

  gemm_kernel<<<MTOT / 256, 256, 0, stream>>>(x_in, Wp, xw);
  dim3 gg((NN + 15) / 16, NB);
  gather_kernel<<<gg, 256, 0, stream>>>(
      (const float4*)xw, rowptr, csrc, cnorm, selfn, bp, (float4*)gcn);
  rnn_kernel<<<(NN + 4) / 5, 256, 0, stream>>>(gcn, Whh, h0, out);
}